// Round 8
// baseline (708.010 us; speedup 1.0000x reference)
//
#include <hip/hip_runtime.h>
#include <hip/hip_bf16.h>
#include <cmath>

using short8  = __attribute__((ext_vector_type(8))) short;
using short4v = __attribute__((ext_vector_type(4))) short;
using f32x16  = __attribute__((ext_vector_type(16))) float;

#define MFMA32B(a,b,c) __builtin_amdgcn_mfma_f32_32x32x16_bf16(a, b, c, 0, 0, 0)

__device__ __forceinline__ unsigned short f2bf(float f) {
    union { float f; unsigned u; } v; v.f = f;
    unsigned u = v.u;
    return (unsigned short)((u + 0x7FFFu + ((u >> 16) & 1u)) >> 16);  // RNE
}
__device__ __forceinline__ float bf2f(unsigned short h) {
    union { unsigned u; float f; } v; v.u = ((unsigned)h) << 16;
    return v.f;
}
__device__ __forceinline__ float softplus(float x) {
    return fmaxf(x, 0.f) + log1pf(expf(-fabsf(x)));  // stable
}

// ---- bf16 B-fragment pack (32x32x16): m = ct*32+(lane&31), k = kk*16+(lane>>5)*8+j ----
__global__ void pack_w_bf16(const float* __restrict__ W, unsigned short* __restrict__ out,
                            int K_real, int M_real, int KT, int CT) {
    int tid = blockIdx.x * blockDim.x + threadIdx.x;
    if (tid >= CT * KT * 64) return;
    int lane = tid & 63;
    int t    = tid >> 6;
    int kk   = t % KT;
    int ct   = t / KT;
    int m  = ct * 32 + (lane & 31);
    int k0 = kk * 16 + ((lane >> 5) << 3);
    short8 v;
#pragma unroll
    for (int j = 0; j < 8; ++j) {
        int k = k0 + j;
        float f = (k < K_real && m < M_real) ? W[(size_t)k * M_real + m] : 0.f;
        v[j] = (short)f2bf(f);
    }
    *(((short8*)out) + tid) = v;
}

// ---------------- fused MLP + loss partials ----------------
// BM=64, 512 threads (8 waves), 1 block/CU ACCEPTED. Register model (R2..R7):
// per-SIMD pool = 512 regs/wave-slot; cap = 512/(waves per SIMD). >2 waves/SIMD
// forces cap<=128 -> spills (acc2 + working set ~190 is irreducible). So: 2
// fat waves/SIMD at 256-reg cap, and maximize per-wave ILP + minimize streams.
//
// CT=2 x RT=2 register blocking: per kk, 2 LDS A-reads + 2 global B-reads feed
// 4 independent MFMAs -> per-MFMA A-bytes and B-bytes both halve vs R7 (1:1).
// W1/W2/W3 each streamed EXACTLY ONCE per block (R7 double-walked W1).
// Pipe estimates/CU: MFMA 123us, LDS-A ~92us, L2-B ~133us.
//
// All-bf16 (absmax ~0). LDS byte layout:
//   [0,65536)      : X bf16 [64][512] rowBytes 1024, swz byte^=(row&15)<<4
//                    -> after L2 done: h2 bf16 same layout
//   [65536,131072) : h1 half bf16 [64][512] rowBytes 1024, same swz
//                    -> after L2: h3 bf16 [64][256] rowBytes 512, same swz form
// Phases: stageX | {L1 half -> L2 partial} x2 | h2epi | L3 | L4+loss.
__global__ __launch_bounds__(512, 2) void fused_mlp(
    const float* __restrict__ Xf, const float* __restrict__ Xr,
    const unsigned short* __restrict__ pW1, const unsigned short* __restrict__ pW2,
    const unsigned short* __restrict__ pW3,
    const float* __restrict__ b1, const float* __restrict__ b2,
    const float* __restrict__ b3, const float* __restrict__ W4,
    const float* __restrict__ b4, float* __restrict__ partials)
{
    __shared__ __align__(16) unsigned char smem[131072];
    __shared__ float red[128];

    const int tidx = threadIdx.x;
    const int wid  = tidx >> 6;      // 0..7
    const int lane = tidx & 63;
    const int l31  = lane & 31;
    const int hi   = lane >> 5;
    const int swz4 = (l31 & 15) << 4;   // row-swizzle term (rows rt*32+l31 share &15)

    const long grow0 = (long)blockIdx.x * 64;   // blocks 0..1023 fake, 1024..2047 real
    const float* X = (grow0 < 65536) ? (Xf + (size_t)grow0 * 512)
                                     : (Xr + (size_t)(grow0 - 65536) * 512);

    // ---- stage X (fp32 HBM -> bf16 LDS): 16 float4/thread ----
    {
        float4 xr[16];
#pragma unroll
        for (int it = 0; it < 16; ++it) {
            int idx = it * 512 + tidx; int r = idx >> 7; int c4 = idx & 127;
            xr[it] = *(const float4*)(X + (size_t)r * 512 + c4 * 4);
        }
#pragma unroll
        for (int it = 0; it < 16; ++it) {
            int idx = it * 512 + tidx; int r = idx >> 7; int c4 = idx & 127;
            short4v s;
            s[0] = (short)f2bf(xr[it].x); s[1] = (short)f2bf(xr[it].y);
            s[2] = (short)f2bf(xr[it].z); s[3] = (short)f2bf(xr[it].w);
            *(short4v*)(smem + r * 1024 + ((c4 * 8) ^ ((r & 15) << 4))) = s;
        }
    }

    f32x16 acc2[2][2];               // persistent across both halves (64 regs)
#pragma unroll
    for (int c = 0; c < 2; ++c)
#pragma unroll
        for (int rt = 0; rt < 2; ++rt)
#pragma unroll
            for (int rg = 0; rg < 16; ++rg) acc2[c][rt][rg] = 0.f;

    __syncthreads();

    for (int h = 0; h < 2; ++h) {
        // ======== L1 half: X[64x512] @ W1[:, h*512..+512) -> h1 half ========
        // CT=2, RT=2: 2 A-reads + 2 B-loads -> 4 MFMAs per kk.
        {
            const unsigned short* bp1a =
                pW1 + (((size_t)(h * 16 + wid * 2 + 0) * 32) * 64 + lane) * 8;
            const unsigned short* bp1b =
                pW1 + (((size_t)(h * 16 + wid * 2 + 1) * 32) * 64 + lane) * 8;
            f32x16 acc1[2][2];
#pragma unroll
            for (int c = 0; c < 2; ++c)
#pragma unroll
                for (int rt = 0; rt < 2; ++rt)
#pragma unroll
                    for (int rg = 0; rg < 16; ++rg) acc1[c][rt][rg] = 0.f;
#pragma unroll 4
            for (int kk = 0; kk < 32; ++kk) {
                int kb = (kk * 16 + hi * 8) * 2;
                short8 a0 = *(const short8*)(smem + l31 * 1024 + (kb ^ swz4));
                short8 a1 = *(const short8*)(smem + (32 + l31) * 1024 + (kb ^ swz4));
                short8 b0 = *(const short8*)(bp1a + (size_t)kk * 512);
                short8 b1 = *(const short8*)(bp1b + (size_t)kk * 512);
                acc1[0][0] = MFMA32B(a0, b0, acc1[0][0]);
                acc1[0][1] = MFMA32B(a1, b0, acc1[0][1]);
                acc1[1][0] = MFMA32B(a0, b1, acc1[1][0]);
                acc1[1][1] = MFMA32B(a1, b1, acc1[1][1]);
            }
            // epilogue: bias+relu -> h1 half (rowBytes 1024)
#pragma unroll
            for (int c = 0; c < 2; ++c) {
                int colq = (wid * 2 + c) * 32 + l31;         // 0..511 within half
                int colg = h * 512 + colq;
                float bias1 = (colg < 1000) ? b1[colg] : 0.f;
#pragma unroll
                for (int rt = 0; rt < 2; ++rt)
#pragma unroll
                    for (int rg = 0; rg < 16; ++rg) {
                        int row = rt * 32 + (rg & 3) + 8 * (rg >> 2) + 4 * hi;
                        float v = fmaxf(acc1[c][rt][rg] + bias1, 0.f);
                        *(unsigned short*)(smem + 65536 + row * 1024 +
                                           ((colq * 2) ^ ((row & 15) << 4))) = f2bf(v);
                    }
            }
        }
        __syncthreads();

        // ======== L2 partial: h1half[64x512] @ W2[h*512.., :] ========
        // CT=2, RT=2 into persistent acc2.
        {
            const unsigned short* bp2a =
                pW2 + (((size_t)(wid * 2 + 0) * 64 + h * 32) * 64 + lane) * 8;
            const unsigned short* bp2b =
                pW2 + (((size_t)(wid * 2 + 1) * 64 + h * 32) * 64 + lane) * 8;
#pragma unroll 4
            for (int kk = 0; kk < 32; ++kk) {
                int kb = (kk * 16 + hi * 8) * 2;
                short8 a0 = *(const short8*)(smem + 65536 + l31 * 1024 + (kb ^ swz4));
                short8 a1 = *(const short8*)(smem + 65536 + (32 + l31) * 1024 + (kb ^ swz4));
                short8 b0 = *(const short8*)(bp2a + (size_t)kk * 512);
                short8 b1 = *(const short8*)(bp2b + (size_t)kk * 512);
                acc2[0][0] = MFMA32B(a0, b0, acc2[0][0]);
                acc2[0][1] = MFMA32B(a1, b0, acc2[0][1]);
                acc2[1][0] = MFMA32B(a0, b1, acc2[1][0]);
                acc2[1][1] = MFMA32B(a1, b1, acc2[1][1]);
            }
        }
        __syncthreads();   // h1half consumed before next L1 overwrites it
    }

    // ======== h2 epilogue: bias+relu -> bf16 at [0,65536) (X region dead) ========
#pragma unroll
    for (int c = 0; c < 2; ++c) {
        int col = (wid * 2 + c) * 32 + l31;
        float bias = (col < 500) ? b2[col] : 0.f;
#pragma unroll
        for (int rt = 0; rt < 2; ++rt)
#pragma unroll
            for (int rg = 0; rg < 16; ++rg) {
                int row = rt * 32 + (rg & 3) + 8 * (rg >> 2) + 4 * hi;
                float v = fmaxf(acc2[c][rt][rg] + bias, 0.f);
                *(unsigned short*)(smem + row * 1024 +
                                   ((col * 2) ^ ((row & 15) << 4))) = f2bf(v);
            }
    }
    __syncthreads();

    // ======== L3: h2[64x512] @ W3 -> h3[64x256] at [65536, 98304) ========
    // 8 ct over 8 waves: CT=1, RT=2.
    {
        const unsigned short* bp3 = pW3 + (((size_t)wid * 32) * 64 + lane) * 8;
        f32x16 acc3[2];
#pragma unroll
        for (int rt = 0; rt < 2; ++rt)
#pragma unroll
            for (int rg = 0; rg < 16; ++rg) acc3[rt][rg] = 0.f;
#pragma unroll 4
        for (int kk = 0; kk < 32; ++kk) {
            int kb = (kk * 16 + hi * 8) * 2;
            short8 a0 = *(const short8*)(smem + l31 * 1024 + (kb ^ swz4));
            short8 a1 = *(const short8*)(smem + (32 + l31) * 1024 + (kb ^ swz4));
            short8 b  = *(const short8*)(bp3 + (size_t)kk * 512);
            acc3[0] = MFMA32B(a0, b, acc3[0]);
            acc3[1] = MFMA32B(a1, b, acc3[1]);
        }
        int col = wid * 32 + l31;
        float bias3 = (col < 250) ? b3[col] : 0.f;
#pragma unroll
        for (int rt = 0; rt < 2; ++rt)
#pragma unroll
            for (int rg = 0; rg < 16; ++rg) {
                int row = rt * 32 + (rg & 3) + 8 * (rg >> 2) + 4 * hi;
                float v = fmaxf(acc3[rt][rg] + bias3, 0.f);
                *(unsigned short*)(smem + 65536 + row * 512 +
                                   ((col * 2) ^ ((row & 15) << 4))) = f2bf(v);
            }
    }
    __syncthreads();

    // ======== L4 + loss: z = h3 . W4 + b4, 8 threads/row ========
    {
        int g  = tidx >> 3;      // row 0..63
        int t8 = tidx & 7;
        float sum = 0.f;
#pragma unroll
        for (int qq = 0; qq < 4; ++qq) {
            int colb = t8 * 32 + qq * 8;
            short8 v = *(const short8*)(smem + 65536 + g * 512 +
                                        ((colb * 2) ^ ((g & 15) << 4)));
#pragma unroll
            for (int j = 0; j < 8; ++j) {
                int cc = colb + j;
                sum += (cc < 250) ? bf2f((unsigned short)v[j]) * W4[cc] : 0.f;
            }
        }
        sum += __shfl_down(sum, 4, 8);
        sum += __shfl_down(sum, 2, 8);
        sum += __shfl_down(sum, 1, 8);
        if (t8 == 0) {
            float z = sum + b4[0];
            bool fake = (grow0 < 65536);
            float spn = softplus(-z);
            red[g]      = fake ? spn : 0.f;               // loss_F part
            red[64 + g] = fake ? softplus(z) : spn;       // loss_D part
        }
    }
    __syncthreads();
    if (tidx == 0) {
        float pF = 0.f, pD = 0.f;
        for (int i = 0; i < 64; ++i) { pF += red[i]; pD += red[64 + i]; }
        partials[(size_t)blockIdx.x * 2]     = pF;
        partials[(size_t)blockIdx.x * 2 + 1] = pD;
    }
}

// ---------------- final reduction ----------------
__global__ void reduce_partials(const float* __restrict__ partials, int nblocks,
                                float* __restrict__ out) {
    __shared__ float sF[256], sD[256];
    float f = 0.f, d = 0.f;
    for (int i = threadIdx.x; i < nblocks; i += 256) {
        f += partials[2 * i];
        d += partials[2 * i + 1];
    }
    sF[threadIdx.x] = f; sD[threadIdx.x] = d;
    __syncthreads();
    for (int s = 128; s > 0; s >>= 1) {
        if (threadIdx.x < s) {
            sF[threadIdx.x] += sF[threadIdx.x + s];
            sD[threadIdx.x] += sD[threadIdx.x + s];
        }
        __syncthreads();
    }
    if (threadIdx.x == 0) { out[0] = sF[0]; out[1] = sD[0]; }
}

extern "C" void kernel_launch(void* const* d_in, const int* in_sizes, int n_in,
                              void* d_out, int out_size, void* d_ws, size_t ws_size,
                              hipStream_t stream) {
    const float* Xf = (const float*)d_in[0];   // repr_xy_hat [65536,512]
    const float* Xr = (const float*)d_in[1];   // repr_xy     [65536,512]
    const float* W1 = (const float*)d_in[2];   // [512,1000]
    const float* b1 = (const float*)d_in[3];
    const float* W2 = (const float*)d_in[4];   // [1000,500]
    const float* b2 = (const float*)d_in[5];
    const float* W3 = (const float*)d_in[6];   // [500,250]
    const float* b3 = (const float*)d_in[7];
    const float* W4 = (const float*)d_in[8];   // [250,1]
    const float* b4 = (const float*)d_in[9];

    // ws layout (ushort elements):
    unsigned short* pW1 = (unsigned short*)d_ws;      // CT32*KT32*64*8 = 524288 (1 MB)
    unsigned short* pW2 = pW1 + 524288;               // CT16*KT64*64*8 = 524288 (1 MB)
    unsigned short* pW3 = pW2 + 524288;               // CT8 *KT32*64*8 = 131072 (256 KB)
    float* partials = (float*)(pW3 + 131072);         // 2048*2 floats (16 KB)

    pack_w_bf16<<<(32 * 32 * 64) / 256, 256, 0, stream>>>(W1, pW1, 512, 1000, 32, 32);
    pack_w_bf16<<<(16 * 64 * 64) / 256, 256, 0, stream>>>(W2, pW2, 1000, 500, 64, 16);
    pack_w_bf16<<<(8 * 32 * 64) / 256, 256, 0, stream>>>(W3, pW3, 500, 250, 32, 8);

    fused_mlp<<<2048, 512, 0, stream>>>(Xf, Xr, pW1, pW2, pW3,
                                        b1, b2, b3, W4, b4, partials);

    reduce_partials<<<1, 256, 0, stream>>>(partials, 2048, (float*)d_out);
}

// Round 9
// 326.738 us; speedup vs baseline: 2.1669x; 2.1669x over previous
//
#include <hip/hip_runtime.h>
#include <hip/hip_bf16.h>
#include <cmath>

using short4v = __attribute__((ext_vector_type(4))) short;
using f32x16  = __attribute__((ext_vector_type(16))) float;
using ll2     = __attribute__((ext_vector_type(2))) long long;

#define MFMA32F8(a,b,c) __builtin_amdgcn_mfma_f32_32x32x16_fp8_fp8(a, b, c, 0, 0, 0)

__device__ __forceinline__ unsigned short f2bf(float f) {
    union { float f; unsigned u; } v; v.f = f;
    unsigned u = v.u;
    return (unsigned short)((u + 0x7FFFu + ((u >> 16) & 1u)) >> 16);  // RNE
}
__device__ __forceinline__ float bf2f(unsigned short h) {
    union { unsigned u; float f; } v; v.u = ((unsigned)h) << 16;
    return v.f;
}
__device__ __forceinline__ float softplus(float x) {
    return fmaxf(x, 0.f) + log1pf(expf(-fabsf(x)));  // stable
}
__device__ __forceinline__ unsigned f4_to_fp8x4(float a, float b, float c, float d) {
    int v = __builtin_amdgcn_cvt_pk_fp8_f32(a, b, 0, false);
    v = __builtin_amdgcn_cvt_pk_fp8_f32(c, d, v, true);
    return (unsigned)v;
}

// ---- fp8 fragment pack, PAIRED kk (16B/lane/kp). Used as MFMA *A* operand.
// m = ct*32+(lane&31); k = (kp*2+s)*16 + (lane>>5)*8 + j  (s=0,1; j=0..7)
__global__ void pack_w_fp8p(const float* __restrict__ W, uint4* __restrict__ out,
                            int K_real, int M_real, int KP, int CT) {
    int tid = blockIdx.x * blockDim.x + threadIdx.x;
    if (tid >= CT * KP * 64) return;
    int lane = tid & 63;
    int t    = tid >> 6;
    int kp   = t % KP;
    int ct   = t / KP;
    int m  = ct * 32 + (lane & 31);
    uint4 o;
    unsigned r[2];
#pragma unroll
    for (int s = 0; s < 2; ++s) {
        int k0 = (kp * 2 + s) * 16 + ((lane >> 5) << 3);
        float f[8];
#pragma unroll
        for (int j = 0; j < 8; ++j) {
            int k = k0 + j;
            f[j] = (k < K_real && m < M_real) ? W[(size_t)k * M_real + m] : 0.f;
        }
        r[0] = f4_to_fp8x4(f[0], f[1], f[2], f[3]);
        r[1] = f4_to_fp8x4(f[4], f[5], f[6], f[7]);
        if (s == 0) { o.x = r[0]; o.y = r[1]; } else { o.z = r[0]; o.w = r[1]; }
    }
    out[tid] = o;
}

// ---- padded biases: [0,1024)=b1, [1024,1536)=b2, [1536,1792)=b3 ----
__global__ void pack_bias(const float* __restrict__ b1, const float* __restrict__ b2,
                          const float* __restrict__ b3, float* __restrict__ out) {
    int i = blockIdx.x * 256 + threadIdx.x;
    if (i < 1024)      out[i] = (i < 1000) ? b1[i] : 0.f;
    else if (i < 1536) { int j = i - 1024; out[i] = (j < 500) ? b2[j] : 0.f; }
    else if (i < 1792) { int j = i - 1536; out[i] = (j < 250) ? b3[j] : 0.f; }
}

// ---------------- fused MLP + loss partials ----------------
// BM=64, 512 thr (8 waves), 1 blk/CU. ALL-fp8 activations/weights; swapped
// MFMA operands (A=weight frag, B=activation frag -> D transposed: lane=batch
// row, regs=feature m). NO persistent accumulators across phases (R8 lesson).
//
// LDS layers are "hi-split" fp8: addr(row,k) = row*L + ((k>>3)&1)*(L/2)
//   + (k>>4)*8 + (k&7), all XOR-swizzled by ((row&15)<<4). This makes a lane's
// TWO consecutive-kk 8B fragments contiguous -> one ds_read_b128 per kk-pair
// (halves LDS instrs; fp8 halves bytes; m134: b128 ~12cyc/CU was the binding
// pipe in R2..R8 at 192cyc vs 128 MFMA).
//
// LDS map: X fp8 [64]x512B at 0 -> h2 fp8 (same region, after L1 done)
//          h1 fp8 [64]x1024B at 32768 -> h3 bf16 [64]x512B (after L2 done)
// Phases: stage | L1 (CT=4/wave, acc 128A) | L2 (CT=2, 64A) | L3 (4 waves,
// CT=2) | L4+loss. Epilogues: 4 consecutive m per reg-quad -> packed 4B writes.
__global__ __launch_bounds__(512, 2) void fused_mlp(
    const float* __restrict__ Xf, const float* __restrict__ Xr,
    const ll2* __restrict__ pW1, const ll2* __restrict__ pW2,
    const ll2* __restrict__ pW3, const float* __restrict__ biasp,
    const float* __restrict__ W4, const float* __restrict__ b4,
    float* __restrict__ partials)
{
    __shared__ __align__(16) unsigned char smem[98304];
    __shared__ float red[128];

    const int tidx = threadIdx.x;
    const int wid  = tidx >> 6;      // 0..7
    const int lane = tidx & 63;
    const int l31  = lane & 31;
    const int hi   = lane >> 5;
    const int swz  = (l31 & 15) << 4;

    const long grow0 = (long)blockIdx.x * 64;   // 0..1023 fake, 1024..2047 real
    const float* X = (grow0 < 65536) ? (Xf + (size_t)grow0 * 512)
                                     : (Xr + (size_t)(grow0 - 65536) * 512);

    // ---- stage X: fp32 HBM -> fp8 hi-split LDS [0,32768) ----
    {
        float4 xr[16];
#pragma unroll
        for (int it = 0; it < 16; ++it) {
            int idx = it * 512 + tidx; int r = idx >> 7; int c4 = idx & 127;
            xr[it] = *(const float4*)(X + (size_t)r * 512 + c4 * 4);
        }
#pragma unroll
        for (int it = 0; it < 16; ++it) {
            int idx = it * 512 + tidx; int r = idx >> 7; int k0 = (idx & 127) * 4;
            int pos = ((k0 >> 3) & 1) * 256 + ((k0 >> 4) << 3) + (k0 & 7);
            *(unsigned*)(smem + r * 512 + (pos ^ ((r & 15) << 4))) =
                f4_to_fp8x4(xr[it].x, xr[it].y, xr[it].z, xr[it].w);
        }
    }
    __syncthreads();

    // ======== L1: h1^T = W1^T(A) x X(B), K=512 (16 kp), CT=4, RT=2 ========
    {
        const ll2* wp0 = pW1 + ((size_t)(wid * 4 + 0) * 16) * 64 + lane;
        const ll2* wp1 = pW1 + ((size_t)(wid * 4 + 1) * 16) * 64 + lane;
        const ll2* wp2 = pW1 + ((size_t)(wid * 4 + 2) * 16) * 64 + lane;
        const ll2* wp3 = pW1 + ((size_t)(wid * 4 + 3) * 16) * 64 + lane;
        f32x16 acc[4][2];
#pragma unroll
        for (int c = 0; c < 4; ++c)
#pragma unroll
            for (int rt = 0; rt < 2; ++rt)
#pragma unroll
                for (int g = 0; g < 16; ++g) acc[c][rt][g] = 0.f;
#pragma unroll 2
        for (int kp = 0; kp < 16; ++kp) {
            int off = (hi * 256 + kp * 16) ^ swz;
            ll2 a0 = *(const ll2*)(smem + l31 * 512 + off);
            ll2 a1 = *(const ll2*)(smem + (32 + l31) * 512 + off);
            ll2 w;
            w = wp0[(size_t)kp * 64];
            acc[0][0] = MFMA32F8(w[0], a0[0], acc[0][0]);
            acc[0][0] = MFMA32F8(w[1], a0[1], acc[0][0]);
            acc[0][1] = MFMA32F8(w[0], a1[0], acc[0][1]);
            acc[0][1] = MFMA32F8(w[1], a1[1], acc[0][1]);
            w = wp1[(size_t)kp * 64];
            acc[1][0] = MFMA32F8(w[0], a0[0], acc[1][0]);
            acc[1][0] = MFMA32F8(w[1], a0[1], acc[1][0]);
            acc[1][1] = MFMA32F8(w[0], a1[0], acc[1][1]);
            acc[1][1] = MFMA32F8(w[1], a1[1], acc[1][1]);
            w = wp2[(size_t)kp * 64];
            acc[2][0] = MFMA32F8(w[0], a0[0], acc[2][0]);
            acc[2][0] = MFMA32F8(w[1], a0[1], acc[2][0]);
            acc[2][1] = MFMA32F8(w[0], a1[0], acc[2][1]);
            acc[2][1] = MFMA32F8(w[1], a1[1], acc[2][1]);
            w = wp3[(size_t)kp * 64];
            acc[3][0] = MFMA32F8(w[0], a0[0], acc[3][0]);
            acc[3][0] = MFMA32F8(w[1], a0[1], acc[3][0]);
            acc[3][1] = MFMA32F8(w[0], a1[0], acc[3][1]);
            acc[3][1] = MFMA32F8(w[1], a1[1], acc[3][1]);
        }
        // epilogue: lane=batch row, reg-quads = 4 consecutive m -> packed 4B
#pragma unroll
        for (int c = 0; c < 4; ++c) {
            int mt = (wid * 4 + c) * 32;
#pragma unroll
            for (int rt = 0; rt < 2; ++rt) {
                int row = rt * 32 + l31;
#pragma unroll
                for (int q = 0; q < 4; ++q) {
                    int mg = mt + q * 8 + hi * 4;          // 0..1023, %4==0
                    float4 bb = *(const float4*)(biasp + mg);
                    float v0 = fmaxf(acc[c][rt][q * 4 + 0] + bb.x, 0.f);
                    float v1 = fmaxf(acc[c][rt][q * 4 + 1] + bb.y, 0.f);
                    float v2 = fmaxf(acc[c][rt][q * 4 + 2] + bb.z, 0.f);
                    float v3 = fmaxf(acc[c][rt][q * 4 + 3] + bb.w, 0.f);
                    int pos = ((mg >> 3) & 1) * 512 + ((mg >> 4) << 3) + (mg & 7);
                    *(unsigned*)(smem + 32768 + row * 1024 + (pos ^ swz)) =
                        f4_to_fp8x4(v0, v1, v2, v3);
                }
            }
        }
    }
    __syncthreads();

    // ======== L2: h2^T = W2^T(A) x h1(B), K=1024 (32 kp), CT=2, RT=2 ========
    {
        const ll2* wp0 = pW2 + ((size_t)(wid * 2 + 0) * 32) * 64 + lane;
        const ll2* wp1 = pW2 + ((size_t)(wid * 2 + 1) * 32) * 64 + lane;
        f32x16 acc[2][2];
#pragma unroll
        for (int c = 0; c < 2; ++c)
#pragma unroll
            for (int rt = 0; rt < 2; ++rt)
#pragma unroll
                for (int g = 0; g < 16; ++g) acc[c][rt][g] = 0.f;
#pragma unroll 2
        for (int kp = 0; kp < 32; ++kp) {
            int off = (hi * 512 + kp * 16) ^ swz;
            ll2 a0 = *(const ll2*)(smem + 32768 + l31 * 1024 + off);
            ll2 a1 = *(const ll2*)(smem + 32768 + (32 + l31) * 1024 + off);
            ll2 w;
            w = wp0[(size_t)kp * 64];
            acc[0][0] = MFMA32F8(w[0], a0[0], acc[0][0]);
            acc[0][0] = MFMA32F8(w[1], a0[1], acc[0][0]);
            acc[0][1] = MFMA32F8(w[0], a1[0], acc[0][1]);
            acc[0][1] = MFMA32F8(w[1], a1[1], acc[0][1]);
            w = wp1[(size_t)kp * 64];
            acc[1][0] = MFMA32F8(w[0], a0[0], acc[1][0]);
            acc[1][0] = MFMA32F8(w[1], a0[1], acc[1][0]);
            acc[1][1] = MFMA32F8(w[0], a1[0], acc[1][1]);
            acc[1][1] = MFMA32F8(w[1], a1[1], acc[1][1]);
        }
        // epilogue -> h2 fp8 at [0,32768) (X dead since L1 barrier)
#pragma unroll
        for (int c = 0; c < 2; ++c) {
            int mt = (wid * 2 + c) * 32;
#pragma unroll
            for (int rt = 0; rt < 2; ++rt) {
                int row = rt * 32 + l31;
#pragma unroll
                for (int q = 0; q < 4; ++q) {
                    int mg = mt + q * 8 + hi * 4;          // 0..511
                    float4 bb = *(const float4*)(biasp + 1024 + mg);
                    float v0 = fmaxf(acc[c][rt][q * 4 + 0] + bb.x, 0.f);
                    float v1 = fmaxf(acc[c][rt][q * 4 + 1] + bb.y, 0.f);
                    float v2 = fmaxf(acc[c][rt][q * 4 + 2] + bb.z, 0.f);
                    float v3 = fmaxf(acc[c][rt][q * 4 + 3] + bb.w, 0.f);
                    int pos = ((mg >> 3) & 1) * 256 + ((mg >> 4) << 3) + (mg & 7);
                    *(unsigned*)(smem + row * 512 + (pos ^ swz)) =
                        f4_to_fp8x4(v0, v1, v2, v3);
                }
            }
        }
    }
    __syncthreads();

    // ======== L3: h3^T = W3^T(A) x h2(B), K=512 (16 kp), waves 0-3, CT=2 ========
    if (wid < 4) {
        const ll2* wp0 = pW3 + ((size_t)(wid * 2 + 0) * 16) * 64 + lane;
        const ll2* wp1 = pW3 + ((size_t)(wid * 2 + 1) * 16) * 64 + lane;
        f32x16 acc[2][2];
#pragma unroll
        for (int c = 0; c < 2; ++c)
#pragma unroll
            for (int rt = 0; rt < 2; ++rt)
#pragma unroll
                for (int g = 0; g < 16; ++g) acc[c][rt][g] = 0.f;
#pragma unroll 2
        for (int kp = 0; kp < 16; ++kp) {
            int off = (hi * 256 + kp * 16) ^ swz;
            ll2 a0 = *(const ll2*)(smem + l31 * 512 + off);
            ll2 a1 = *(const ll2*)(smem + (32 + l31) * 512 + off);
            ll2 w;
            w = wp0[(size_t)kp * 64];
            acc[0][0] = MFMA32F8(w[0], a0[0], acc[0][0]);
            acc[0][0] = MFMA32F8(w[1], a0[1], acc[0][0]);
            acc[0][1] = MFMA32F8(w[0], a1[0], acc[0][1]);
            acc[0][1] = MFMA32F8(w[1], a1[1], acc[0][1]);
            w = wp1[(size_t)kp * 64];
            acc[1][0] = MFMA32F8(w[0], a0[0], acc[1][0]);
            acc[1][0] = MFMA32F8(w[1], a0[1], acc[1][0]);
            acc[1][1] = MFMA32F8(w[0], a1[0], acc[1][1]);
            acc[1][1] = MFMA32F8(w[1], a1[1], acc[1][1]);
        }
        // epilogue -> h3 bf16 ROW-MAJOR [64]x512B at 32768 (h1 dead)
#pragma unroll
        for (int c = 0; c < 2; ++c) {
            int mt = (wid * 2 + c) * 32;
#pragma unroll
            for (int rt = 0; rt < 2; ++rt) {
                int row = rt * 32 + l31;
#pragma unroll
                for (int q = 0; q < 4; ++q) {
                    int mg = mt + q * 8 + hi * 4;          // 0..255
                    float4 bb = *(const float4*)(biasp + 1536 + mg);
                    short4v s;
                    s[0] = (short)f2bf(fmaxf(acc[c][rt][q * 4 + 0] + bb.x, 0.f));
                    s[1] = (short)f2bf(fmaxf(acc[c][rt][q * 4 + 1] + bb.y, 0.f));
                    s[2] = (short)f2bf(fmaxf(acc[c][rt][q * 4 + 2] + bb.z, 0.f));
                    s[3] = (short)f2bf(fmaxf(acc[c][rt][q * 4 + 3] + bb.w, 0.f));
                    *(short4v*)(smem + 32768 + row * 512 + ((mg * 2) ^ swz)) = s;
                }
            }
        }
    }
    __syncthreads();

    // ======== L4 + loss: z = h3 . W4 + b4, 8 threads/row ========
    {
        int g  = tidx >> 3;      // row 0..63
        int t8 = tidx & 7;
        int gs = (g & 15) << 4;
        float sum = 0.f;
#pragma unroll
        for (int o = 0; o < 4; ++o) {
            int colb = t8 * 32 + o * 8;
            short4v v0 = *(const short4v*)(smem + 32768 + g * 512 + ((colb * 2) ^ gs));
            short4v v1 = *(const short4v*)(smem + 32768 + g * 512 + ((colb * 2 + 8) ^ gs));
#pragma unroll
            for (int j = 0; j < 4; ++j) {
                int c0 = colb + j, c1 = colb + 4 + j;
                if (c0 < 250) sum += bf2f((unsigned short)v0[j]) * W4[c0];
                if (c1 < 250) sum += bf2f((unsigned short)v1[j]) * W4[c1];
            }
        }
        sum += __shfl_down(sum, 4, 8);
        sum += __shfl_down(sum, 2, 8);
        sum += __shfl_down(sum, 1, 8);
        if (t8 == 0) {
            float z = sum + b4[0];
            bool fake = (grow0 < 65536);
            float spn = softplus(-z);
            red[g]      = fake ? spn : 0.f;               // loss_F part
            red[64 + g] = fake ? softplus(z) : spn;       // loss_D part
        }
    }
    __syncthreads();
    if (tidx == 0) {
        float pF = 0.f, pD = 0.f;
        for (int i = 0; i < 64; ++i) { pF += red[i]; pD += red[64 + i]; }
        partials[(size_t)blockIdx.x * 2]     = pF;
        partials[(size_t)blockIdx.x * 2 + 1] = pD;
    }
}

// ---------------- final reduction ----------------
__global__ void reduce_partials(const float* __restrict__ partials, int nblocks,
                                float* __restrict__ out) {
    __shared__ float sF[256], sD[256];
    float f = 0.f, d = 0.f;
    for (int i = threadIdx.x; i < nblocks; i += 256) {
        f += partials[2 * i];
        d += partials[2 * i + 1];
    }
    sF[threadIdx.x] = f; sD[threadIdx.x] = d;
    __syncthreads();
    for (int s = 128; s > 0; s >>= 1) {
        if (threadIdx.x < s) {
            sF[threadIdx.x] += sF[threadIdx.x + s];
            sD[threadIdx.x] += sD[threadIdx.x + s];
        }
        __syncthreads();
    }
    if (threadIdx.x == 0) { out[0] = sF[0]; out[1] = sD[0]; }
}

extern "C" void kernel_launch(void* const* d_in, const int* in_sizes, int n_in,
                              void* d_out, int out_size, void* d_ws, size_t ws_size,
                              hipStream_t stream) {
    const float* Xf = (const float*)d_in[0];   // repr_xy_hat [65536,512]
    const float* Xr = (const float*)d_in[1];   // repr_xy     [65536,512]
    const float* W1 = (const float*)d_in[2];   // [512,1000]
    const float* b1 = (const float*)d_in[3];
    const float* W2 = (const float*)d_in[4];   // [1000,500]
    const float* b2 = (const float*)d_in[5];
    const float* W3 = (const float*)d_in[6];   // [500,250]
    const float* b3 = (const float*)d_in[7];
    const float* W4 = (const float*)d_in[8];   // [250,1]
    const float* b4 = (const float*)d_in[9];

    // ws layout (16B units for packs):
    // pW1: CT32 x KP16 x 64 lanes x 16B = 512 KB
    // pW2: CT16 x KP32 x 64 x 16B       = 512 KB
    // pW3: CT8  x KP16 x 64 x 16B       = 128 KB
    uint4* pW1 = (uint4*)d_ws;
    uint4* pW2 = pW1 + 32 * 16 * 64;
    uint4* pW3 = pW2 + 16 * 32 * 64;
    float* biasp = (float*)(pW3 + 8 * 16 * 64);          // 1792 floats
    float* partials = biasp + 2048;                      // 2048*2 floats

    pack_w_fp8p<<<(32 * 16 * 64) / 256, 256, 0, stream>>>(W1, pW1, 512, 1000, 16, 32);
    pack_w_fp8p<<<(16 * 32 * 64) / 256, 256, 0, stream>>>(W2, pW2, 1000, 500, 32, 16);
    pack_w_fp8p<<<(8 * 16 * 64) / 256, 256, 0, stream>>>(W3, pW3, 500, 250, 16, 8);
    pack_bias<<<7, 256, 0, stream>>>(b1, b2, b3, biasp);

    fused_mlp<<<2048, 512, 0, stream>>>(Xf, Xr, (const ll2*)pW1, (const ll2*)pW2,
                                        (const ll2*)pW3, biasp, W4, b4, partials);

    reduce_partials<<<1, 256, 0, stream>>>(partials, 2048, (float*)d_out);
}

// Round 10
// 278.689 us; speedup vs baseline: 2.5405x; 1.1724x over previous
//
#include <hip/hip_runtime.h>
#include <hip/hip_bf16.h>
#include <cmath>

using short4v = __attribute__((ext_vector_type(4))) short;
using f32x16  = __attribute__((ext_vector_type(16))) float;
using ll2     = __attribute__((ext_vector_type(2))) long long;

#define MFMA32F8(a,b,c) __builtin_amdgcn_mfma_f32_32x32x16_fp8_fp8(a, b, c, 0, 0, 0)

__device__ __forceinline__ unsigned short f2bf(float f) {
    union { float f; unsigned u; } v; v.f = f;
    unsigned u = v.u;
    return (unsigned short)((u + 0x7FFFu + ((u >> 16) & 1u)) >> 16);  // RNE
}
__device__ __forceinline__ float bf2f(unsigned short h) {
    union { unsigned u; float f; } v; v.u = ((unsigned)h) << 16;
    return v.f;
}
__device__ __forceinline__ float softplus(float x) {
    return fmaxf(x, 0.f) + log1pf(expf(-fabsf(x)));  // stable
}
__device__ __forceinline__ unsigned f4_to_fp8x4(float a, float b, float c, float d) {
    int v = __builtin_amdgcn_cvt_pk_fp8_f32(a, b, 0, false);
    v = __builtin_amdgcn_cvt_pk_fp8_f32(c, d, v, true);
    return (unsigned)v;
}

// ---- fp8 fragment pack, PAIRED kk (16B/lane/kp). Used as MFMA *A* operand.
// m = ct*32+(lane&31); k = (kp*2+s)*16 + (lane>>5)*8 + j  (s=0,1; j=0..7)
__global__ void pack_w_fp8p(const float* __restrict__ W, uint4* __restrict__ out,
                            int K_real, int M_real, int KP, int CT) {
    int tid = blockIdx.x * blockDim.x + threadIdx.x;
    if (tid >= CT * KP * 64) return;
    int lane = tid & 63;
    int t    = tid >> 6;
    int kp   = t % KP;
    int ct   = t / KP;
    int m  = ct * 32 + (lane & 31);
    uint4 o;
    unsigned r[2];
#pragma unroll
    for (int s = 0; s < 2; ++s) {
        int k0 = (kp * 2 + s) * 16 + ((lane >> 5) << 3);
        float f[8];
#pragma unroll
        for (int j = 0; j < 8; ++j) {
            int k = k0 + j;
            f[j] = (k < K_real && m < M_real) ? W[(size_t)k * M_real + m] : 0.f;
        }
        r[0] = f4_to_fp8x4(f[0], f[1], f[2], f[3]);
        r[1] = f4_to_fp8x4(f[4], f[5], f[6], f[7]);
        if (s == 0) { o.x = r[0]; o.y = r[1]; } else { o.z = r[0]; o.w = r[1]; }
    }
    out[tid] = o;
}

// ---- padded biases: [0,1024)=b1, [1024,1536)=b2, [1536,1792)=b3 ----
__global__ void pack_bias(const float* __restrict__ b1, const float* __restrict__ b2,
                          const float* __restrict__ b3, float* __restrict__ out) {
    int i = blockIdx.x * 256 + threadIdx.x;
    if (i < 1024)      out[i] = (i < 1000) ? b1[i] : 0.f;
    else if (i < 1536) { int j = i - 1024; out[i] = (j < 500) ? b2[j] : 0.f; }
    else if (i < 1792) { int j = i - 1536; out[i] = (j < 250) ? b3[j] : 0.f; }
}

// ---------------- fused MLP + loss partials ----------------
// R10: TWO blocks/CU. R9 structure (all-fp8, swapped operands, paired-kk b128,
// no persistent acc) but: L1 split into 2 ct-half passes (CT=2 -> 64A transient,
// X re-staged per pass in 8KB K-chunks), LDS 72KB (2x72=145<=160KB), and
// __launch_bounds__(512,4) -> reg cap 128 (R3-calibrated; compiler splits
// ~64V/64A; true demand ~64A+~55V). WRITE_SIZE is the spill tripwire.
//
// LDS map (72KB):
//   [0,8192)       : X fp8 chunk [64]x128B hi-split, swz ^((row&7)<<4)
//                    (also float red[128] at [0,512) after L1 — X dead)
//   [8192,73728)   : h1 fp8 [64]x1024B hi-split, swz ^((row&15)<<4)
//                    -> h2 fp8 [64]x512B at [8192,40960) after L2
//                    -> h3 bf16 [64]x512B at [40960,73728) after L3
// Phases: {stage Xchunk|L1 kp x4}x4 x2 passes | L2 | h2epi | L3 | L4+loss.
__global__ __launch_bounds__(512, 4) void fused_mlp(
    const float* __restrict__ Xf, const float* __restrict__ Xr,
    const ll2* __restrict__ pW1, const ll2* __restrict__ pW2,
    const ll2* __restrict__ pW3, const float* __restrict__ biasp,
    const float* __restrict__ W4, const float* __restrict__ b4,
    float* __restrict__ partials)
{
    __shared__ __align__(16) unsigned char smem[73728];
    float* red = (float*)smem;          // overlaps X-chunk region (dead after L1)

    const int tidx = threadIdx.x;
    const int wid  = tidx >> 6;      // 0..7
    const int lane = tidx & 63;
    const int l31  = lane & 31;
    const int hi   = lane >> 5;
    const int swzx = (l31 & 7) << 4;    // X-chunk rows (128B): 8 16B slots
    const int swz  = (l31 & 15) << 4;   // h1/h2/h3 rows

    const long grow0 = (long)blockIdx.x * 64;   // 0..1023 fake, 1024..2047 real
    const float* X = (grow0 < 65536) ? (Xf + (size_t)grow0 * 512)
                                     : (Xr + (size_t)(grow0 - 65536) * 512);

    // ======== L1: h1^T = W1^T(A) x X(B); 2 ct-half passes, X chunk-staged ========
#pragma unroll 1
    for (int p = 0; p < 2; ++p) {
        const ll2* wp0 = pW1 + ((size_t)(p * 16 + wid * 2 + 0) * 16) * 64 + lane;
        const ll2* wp1 = pW1 + ((size_t)(p * 16 + wid * 2 + 1) * 16) * 64 + lane;
        f32x16 acc[2][2];
#pragma unroll
        for (int c = 0; c < 2; ++c)
#pragma unroll
            for (int rt = 0; rt < 2; ++rt)
#pragma unroll
                for (int g = 0; g < 16; ++g) acc[c][rt][g] = 0.f;

#pragma unroll 1
        for (int ch = 0; ch < 4; ++ch) {
            // stage X[:, ch*128..+128) -> fp8 hi-split [0,8192)
            float4 xr[4];
#pragma unroll
            for (int it = 0; it < 4; ++it) {
                int idx = it * 512 + tidx; int r = idx >> 5; int q = idx & 31;
                xr[it] = *(const float4*)(X + (size_t)r * 512 + ch * 128 + q * 4);
            }
            __syncthreads();            // prior chunk's A-reads done
#pragma unroll
            for (int it = 0; it < 4; ++it) {
                int idx = it * 512 + tidx; int r = idx >> 5; int k0 = (idx & 31) * 4;
                int pos = ((k0 >> 3) & 1) * 64 + ((k0 >> 4) << 3) + (k0 & 7);
                *(unsigned*)(smem + r * 128 + (pos ^ ((r & 7) << 4))) =
                    f4_to_fp8x4(xr[it].x, xr[it].y, xr[it].z, xr[it].w);
            }
            __syncthreads();
            // compute: 4 kp (K=128) x 8 MFMA
#pragma unroll
            for (int kpl = 0; kpl < 4; ++kpl) {
                int off = (hi * 64 + kpl * 16) ^ swzx;
                ll2 a0 = *(const ll2*)(smem + l31 * 128 + off);
                ll2 a1 = *(const ll2*)(smem + (32 + l31) * 128 + off);
                ll2 w0 = wp0[(size_t)(ch * 4 + kpl) * 64];
                ll2 w1 = wp1[(size_t)(ch * 4 + kpl) * 64];
                acc[0][0] = MFMA32F8(w0[0], a0[0], acc[0][0]);
                acc[0][0] = MFMA32F8(w0[1], a0[1], acc[0][0]);
                acc[0][1] = MFMA32F8(w0[0], a1[0], acc[0][1]);
                acc[0][1] = MFMA32F8(w0[1], a1[1], acc[0][1]);
                acc[1][0] = MFMA32F8(w1[0], a0[0], acc[1][0]);
                acc[1][0] = MFMA32F8(w1[1], a0[1], acc[1][0]);
                acc[1][1] = MFMA32F8(w1[0], a1[0], acc[1][1]);
                acc[1][1] = MFMA32F8(w1[1], a1[1], acc[1][1]);
            }
            // no trailing barrier: next chunk's pre-write barrier covers WAR
        }
        // epilogue -> h1 cols [p*512, p*512+512); disjoint from X region.
        // (Next pass's first barrier orders these writes vs everything.)
#pragma unroll
        for (int c = 0; c < 2; ++c) {
            int mt = (p * 16 + wid * 2 + c) * 32;
#pragma unroll
            for (int rt = 0; rt < 2; ++rt) {
                int row = rt * 32 + l31;
#pragma unroll
                for (int q = 0; q < 4; ++q) {
                    int mg = mt + q * 8 + hi * 4;          // global h1 col, %4==0
                    float4 bb = *(const float4*)(biasp + mg);
                    float v0 = fmaxf(acc[c][rt][q * 4 + 0] + bb.x, 0.f);
                    float v1 = fmaxf(acc[c][rt][q * 4 + 1] + bb.y, 0.f);
                    float v2 = fmaxf(acc[c][rt][q * 4 + 2] + bb.z, 0.f);
                    float v3 = fmaxf(acc[c][rt][q * 4 + 3] + bb.w, 0.f);
                    int pos = ((mg >> 3) & 1) * 512 + ((mg >> 4) << 3) + (mg & 7);
                    *(unsigned*)(smem + 8192 + row * 1024 + (pos ^ swz)) =
                        f4_to_fp8x4(v0, v1, v2, v3);
                }
            }
        }
    }
    __syncthreads();

    // ======== L2: h2^T = W2^T(A) x h1(B), K=1024 (32 kp), CT=2, RT=2 ========
    {
        const ll2* wp0 = pW2 + ((size_t)(wid * 2 + 0) * 32) * 64 + lane;
        const ll2* wp1 = pW2 + ((size_t)(wid * 2 + 1) * 32) * 64 + lane;
        f32x16 acc[2][2];
#pragma unroll
        for (int c = 0; c < 2; ++c)
#pragma unroll
            for (int rt = 0; rt < 2; ++rt)
#pragma unroll
                for (int g = 0; g < 16; ++g) acc[c][rt][g] = 0.f;
#pragma unroll 2
        for (int kp = 0; kp < 32; ++kp) {
            int off = (hi * 512 + kp * 16) ^ swz;
            ll2 a0 = *(const ll2*)(smem + 8192 + l31 * 1024 + off);
            ll2 a1 = *(const ll2*)(smem + 8192 + (32 + l31) * 1024 + off);
            ll2 w0 = wp0[(size_t)kp * 64];
            ll2 w1 = wp1[(size_t)kp * 64];
            acc[0][0] = MFMA32F8(w0[0], a0[0], acc[0][0]);
            acc[0][0] = MFMA32F8(w0[1], a0[1], acc[0][0]);
            acc[0][1] = MFMA32F8(w0[0], a1[0], acc[0][1]);
            acc[0][1] = MFMA32F8(w0[1], a1[1], acc[0][1]);
            acc[1][0] = MFMA32F8(w1[0], a0[0], acc[1][0]);
            acc[1][0] = MFMA32F8(w1[1], a0[1], acc[1][0]);
            acc[1][1] = MFMA32F8(w1[0], a1[0], acc[1][1]);
            acc[1][1] = MFMA32F8(w1[1], a1[1], acc[1][1]);
        }
        __syncthreads();   // ALL h1 reads done before h2 overwrites the region
        // epilogue -> h2 fp8 [64]x512B at [8192,40960)
#pragma unroll
        for (int c = 0; c < 2; ++c) {
            int mt = (wid * 2 + c) * 32;
#pragma unroll
            for (int rt = 0; rt < 2; ++rt) {
                int row = rt * 32 + l31;
#pragma unroll
                for (int q = 0; q < 4; ++q) {
                    int mg = mt + q * 8 + hi * 4;          // 0..511
                    float4 bb = *(const float4*)(biasp + 1024 + mg);
                    float v0 = fmaxf(acc[c][rt][q * 4 + 0] + bb.x, 0.f);
                    float v1 = fmaxf(acc[c][rt][q * 4 + 1] + bb.y, 0.f);
                    float v2 = fmaxf(acc[c][rt][q * 4 + 2] + bb.z, 0.f);
                    float v3 = fmaxf(acc[c][rt][q * 4 + 3] + bb.w, 0.f);
                    int pos = ((mg >> 3) & 1) * 256 + ((mg >> 4) << 3) + (mg & 7);
                    *(unsigned*)(smem + 8192 + row * 512 + (pos ^ swz)) =
                        f4_to_fp8x4(v0, v1, v2, v3);
                }
            }
        }
    }
    __syncthreads();

    // ======== L3: h3^T = W3^T(A) x h2(B), K=512 (16 kp), ALL 8 waves CT=1 ========
    {
        const ll2* wp = pW3 + ((size_t)wid * 16) * 64 + lane;
        f32x16 acc3[2];
#pragma unroll
        for (int rt = 0; rt < 2; ++rt)
#pragma unroll
            for (int g = 0; g < 16; ++g) acc3[rt][g] = 0.f;
#pragma unroll 2
        for (int kp = 0; kp < 16; ++kp) {
            int off = (hi * 256 + kp * 16) ^ swz;
            ll2 a0 = *(const ll2*)(smem + 8192 + l31 * 512 + off);
            ll2 a1 = *(const ll2*)(smem + 8192 + (32 + l31) * 512 + off);
            ll2 w = wp[(size_t)kp * 64];
            acc3[0] = MFMA32F8(w[0], a0[0], acc3[0]);
            acc3[0] = MFMA32F8(w[1], a0[1], acc3[0]);
            acc3[1] = MFMA32F8(w[0], a1[0], acc3[1]);
            acc3[1] = MFMA32F8(w[1], a1[1], acc3[1]);
        }
        // epilogue -> h3 bf16 [64]x512B at [40960,73728): disjoint from h2
        // reads region, so no barrier needed before these writes.
        int mt = wid * 32;
#pragma unroll
        for (int rt = 0; rt < 2; ++rt) {
            int row = rt * 32 + l31;
#pragma unroll
            for (int q = 0; q < 4; ++q) {
                int mg = mt + q * 8 + hi * 4;              // 0..255
                float4 bb = *(const float4*)(biasp + 1536 + mg);
                short4v s;
                s[0] = (short)f2bf(fmaxf(acc3[rt][q * 4 + 0] + bb.x, 0.f));
                s[1] = (short)f2bf(fmaxf(acc3[rt][q * 4 + 1] + bb.y, 0.f));
                s[2] = (short)f2bf(fmaxf(acc3[rt][q * 4 + 2] + bb.z, 0.f));
                s[3] = (short)f2bf(fmaxf(acc3[rt][q * 4 + 3] + bb.w, 0.f));
                *(short4v*)(smem + 40960 + row * 512 + ((mg * 2) ^ swz)) = s;
            }
        }
    }
    __syncthreads();

    // ======== L4 + loss: z = h3 . W4 + b4, 8 threads/row ========
    {
        int g  = tidx >> 3;      // row 0..63
        int t8 = tidx & 7;
        int gs = (g & 15) << 4;
        float sum = 0.f;
#pragma unroll
        for (int o = 0; o < 4; ++o) {
            int colb = t8 * 32 + o * 8;
            short4v v0 = *(const short4v*)(smem + 40960 + g * 512 + ((colb * 2) ^ gs));
            short4v v1 = *(const short4v*)(smem + 40960 + g * 512 + ((colb * 2 + 8) ^ gs));
#pragma unroll
            for (int j = 0; j < 4; ++j) {
                int c0 = colb + j, c1 = colb + 4 + j;
                if (c0 < 250) sum += bf2f((unsigned short)v0[j]) * W4[c0];
                if (c1 < 250) sum += bf2f((unsigned short)v1[j]) * W4[c1];
            }
        }
        sum += __shfl_down(sum, 4, 8);
        sum += __shfl_down(sum, 2, 8);
        sum += __shfl_down(sum, 1, 8);
        if (t8 == 0) {
            float z = sum + b4[0];
            bool fake = (grow0 < 65536);
            float spn = softplus(-z);
            red[g]      = fake ? spn : 0.f;               // loss_F part
            red[64 + g] = fake ? softplus(z) : spn;       // loss_D part
        }
    }
    __syncthreads();
    if (tidx == 0) {
        float pF = 0.f, pD = 0.f;
        for (int i = 0; i < 64; ++i) { pF += red[i]; pD += red[64 + i]; }
        partials[(size_t)blockIdx.x * 2]     = pF;
        partials[(size_t)blockIdx.x * 2 + 1] = pD;
    }
}

// ---------------- final reduction ----------------
__global__ void reduce_partials(const float* __restrict__ partials, int nblocks,
                                float* __restrict__ out) {
    __shared__ float sF[256], sD[256];
    float f = 0.f, d = 0.f;
    for (int i = threadIdx.x; i < nblocks; i += 256) {
        f += partials[2 * i];
        d += partials[2 * i + 1];
    }
    sF[threadIdx.x] = f; sD[threadIdx.x] = d;
    __syncthreads();
    for (int s = 128; s > 0; s >>= 1) {
        if (threadIdx.x < s) {
            sF[threadIdx.x] += sF[threadIdx.x + s];
            sD[threadIdx.x] += sD[threadIdx.x + s];
        }
        __syncthreads();
    }
    if (threadIdx.x == 0) { out[0] = sF[0]; out[1] = sD[0]; }
}

extern "C" void kernel_launch(void* const* d_in, const int* in_sizes, int n_in,
                              void* d_out, int out_size, void* d_ws, size_t ws_size,
                              hipStream_t stream) {
    const float* Xf = (const float*)d_in[0];   // repr_xy_hat [65536,512]
    const float* Xr = (const float*)d_in[1];   // repr_xy     [65536,512]
    const float* W1 = (const float*)d_in[2];   // [512,1000]
    const float* b1 = (const float*)d_in[3];
    const float* W2 = (const float*)d_in[4];   // [1000,500]
    const float* b2 = (const float*)d_in[5];
    const float* W3 = (const float*)d_in[6];   // [500,250]
    const float* b3 = (const float*)d_in[7];
    const float* W4 = (const float*)d_in[8];   // [250,1]
    const float* b4 = (const float*)d_in[9];

    // ws layout (16B units for packs):
    uint4* pW1 = (uint4*)d_ws;                    // CT32 x KP16 x 64 = 512 KB
    uint4* pW2 = pW1 + 32 * 16 * 64;              // CT16 x KP32 x 64 = 512 KB
    uint4* pW3 = pW2 + 16 * 32 * 64;              // CT8  x KP16 x 64 = 128 KB
    float* biasp = (float*)(pW3 + 8 * 16 * 64);   // 1792 floats
    float* partials = biasp + 2048;               // 2048*2 floats

    pack_w_fp8p<<<(32 * 16 * 64) / 256, 256, 0, stream>>>(W1, pW1, 512, 1000, 16, 32);
    pack_w_fp8p<<<(16 * 32 * 64) / 256, 256, 0, stream>>>(W2, pW2, 1000, 500, 32, 16);
    pack_w_fp8p<<<(8 * 16 * 64) / 256, 256, 0, stream>>>(W3, pW3, 500, 250, 16, 8);
    pack_bias<<<7, 256, 0, stream>>>(b1, b2, b3, biasp);

    fused_mlp<<<2048, 512, 0, stream>>>(Xf, Xr, (const ll2*)pW1, (const ll2*)pW2,
                                        (const ll2*)pW3, biasp, W4, b4, partials);

    reduce_partials<<<1, 256, 0, stream>>>(partials, 2048, (float*)d_out);
}

// Round 11
// 213.165 us; speedup vs baseline: 3.3214x; 1.3074x over previous
//
#include <hip/hip_runtime.h>
#include <hip/hip_bf16.h>
#include <cmath>

using short4v = __attribute__((ext_vector_type(4))) short;
using f32x16  = __attribute__((ext_vector_type(16))) float;
using int8v   = __attribute__((ext_vector_type(8))) int;

// MX-scaled fp8 MFMA, K=64/instr, scales forced to 1.0 (E8M0=0x7F in every byte
// so any opsel selection reads 127 -> 2^0). cbsz=0/blgp=0 -> both operands FP8 E4M3.
#define MFMASC(a,b,c) __builtin_amdgcn_mfma_scale_f32_32x32x64_f8f6f4( \
    a, b, c, 0, 0, 0, 0x7F7F7F7F, 0, 0x7F7F7F7F)

__device__ __forceinline__ unsigned short f2bf(float f) {
    union { float f; unsigned u; } v; v.f = f;
    unsigned u = v.u;
    return (unsigned short)((u + 0x7FFFu + ((u >> 16) & 1u)) >> 16);  // RNE
}
__device__ __forceinline__ float bf2f(unsigned short h) {
    union { unsigned u; float f; } v; v.u = ((unsigned)h) << 16;
    return v.f;
}
__device__ __forceinline__ float softplus(float x) {
    return fmaxf(x, 0.f) + log1pf(expf(-fabsf(x)));  // stable
}
__device__ __forceinline__ unsigned f4_to_fp8x4(float a, float b, float c, float d) {
    int v = __builtin_amdgcn_cvt_pk_fp8_f32(a, b, 0, false);
    v = __builtin_amdgcn_cvt_pk_fp8_f32(c, d, v, true);
    return (unsigned)v;
}
__device__ __forceinline__ int8v mk8(uint4 a, uint4 b) {
    int8v r;
    r[0] = (int)a.x; r[1] = (int)a.y; r[2] = (int)a.z; r[3] = (int)a.w;
    r[4] = (int)b.x; r[5] = (int)b.y; r[6] = (int)b.z; r[7] = (int)b.w;
    return r;
}

// ---- fp8 fragment pack, K=64 groups (32B/lane/kg), used as MFMA *A* operand.
// m = ct*32+(lane&31); k = kg*64 + (lane>>5)*32 + j  (j=0..31 across 8 dwords)
__global__ void pack_w_fp8g(const float* __restrict__ W, uint4* __restrict__ out,
                            int K_real, int M_real, int KG, int CT) {
    int tid = blockIdx.x * blockDim.x + threadIdx.x;
    if (tid >= CT * KG * 64) return;
    int lane = tid & 63;
    int t    = tid >> 6;
    int kg   = t % KG;
    int ct   = t / KG;
    int m  = ct * 32 + (lane & 31);
    int kb = kg * 64 + ((lane >> 5) << 5);
    float f[32];
#pragma unroll
    for (int j = 0; j < 32; ++j) {
        int k = kb + j;
        f[j] = (k < K_real && m < M_real) ? W[(size_t)k * M_real + m] : 0.f;
    }
    uint4 o0, o1;
    o0.x = f4_to_fp8x4(f[0],  f[1],  f[2],  f[3]);
    o0.y = f4_to_fp8x4(f[4],  f[5],  f[6],  f[7]);
    o0.z = f4_to_fp8x4(f[8],  f[9],  f[10], f[11]);
    o0.w = f4_to_fp8x4(f[12], f[13], f[14], f[15]);
    o1.x = f4_to_fp8x4(f[16], f[17], f[18], f[19]);
    o1.y = f4_to_fp8x4(f[20], f[21], f[22], f[23]);
    o1.z = f4_to_fp8x4(f[24], f[25], f[26], f[27]);
    o1.w = f4_to_fp8x4(f[28], f[29], f[30], f[31]);
    out[(size_t)tid * 2]     = o0;
    out[(size_t)tid * 2 + 1] = o1;
}

// ---- padded biases: [0,1024)=b1, [1024,1536)=b2, [1536,1792)=b3 ----
__global__ void pack_bias(const float* __restrict__ b1, const float* __restrict__ b2,
                          const float* __restrict__ b3, float* __restrict__ out) {
    int i = blockIdx.x * 256 + threadIdx.x;
    if (i < 1024)      out[i] = (i < 1000) ? b1[i] : 0.f;
    else if (i < 1536) { int j = i - 1024; out[i] = (j < 500) ? b2[j] : 0.f; }
    else if (i < 1792) { int j = i - 1536; out[i] = (j < 250) ? b3[j] : 0.f; }
}

// ---------------- fused MLP + loss partials ----------------
// R11 = R10 structure (2 blocks/CU, all-fp8, swapped operands, no persistent
// acc, 2-pass chunked L1) with the MFMA swapped to MX-scaled 32x32x64 fp8
// (2x rate, scales==1.0). Reads are 32B consecutive-k per lane (two b128s),
// so the hi-split layout is dropped: fp8 tensor addr(r,k) = r*L +
// ((k&~15) ^ ((r&15)<<4)) + (k&15)  (== (k ^ swz) for 16B-internal-aligned k).
//
// LDS map (73728 B):
//   [0,8192)     : X fp8 chunk [64]x128B, swz ((r&7)<<4); red[] after L1
//   [8192,73728) : h1 fp8 [64]x1024B -> h2 fp8 [64]x512B at 8192
//                  -> h3 bf16 [64]x512B at 40960
// launch_bounds(512,4): reg cap 128 (64V+64A split); per-kg operands 32V ->
// R10's proven no-spill shape. WRITE_SIZE is the spill tripwire.
__global__ __launch_bounds__(512, 4) void fused_mlp(
    const float* __restrict__ Xf, const float* __restrict__ Xr,
    const uint4* __restrict__ pW1, const uint4* __restrict__ pW2,
    const uint4* __restrict__ pW3, const float* __restrict__ biasp,
    const float* __restrict__ W4, const float* __restrict__ b4,
    float* __restrict__ partials)
{
    __shared__ __align__(16) unsigned char smem[73728];
    float* red = (float*)smem;          // overlaps X-chunk region (dead after L1)

    const int tidx = threadIdx.x;
    const int wid  = tidx >> 6;      // 0..7
    const int lane = tidx & 63;
    const int l31  = lane & 31;
    const int hi   = lane >> 5;
    const int swzx = (l31 & 7) << 4;    // X-chunk rows (128B rows)
    const int swz  = (l31 & 15) << 4;   // h1/h2/h3 rows

    const long grow0 = (long)blockIdx.x * 64;   // 0..1023 fake, 1024..2047 real
    const float* X = (grow0 < 65536) ? (Xf + (size_t)grow0 * 512)
                                     : (Xr + (size_t)(grow0 - 65536) * 512);

    // ======== L1: h1^T = W1^T(A) x X(B); 2 ct-half passes, X chunk-staged ========
#pragma unroll 1
    for (int p = 0; p < 2; ++p) {
        const uint4* wpA = pW1 + ((size_t)((p * 16 + wid * 2 + 0) * 8) * 64 + lane) * 2;
        const uint4* wpB = pW1 + ((size_t)((p * 16 + wid * 2 + 1) * 8) * 64 + lane) * 2;
        f32x16 acc[2][2];
#pragma unroll
        for (int c = 0; c < 2; ++c)
#pragma unroll
            for (int rt = 0; rt < 2; ++rt)
#pragma unroll
                for (int g = 0; g < 16; ++g) acc[c][rt][g] = 0.f;

#pragma unroll 1
        for (int ch = 0; ch < 4; ++ch) {
            // stage X[:, ch*128..+128) -> fp8 [0,8192)
            float4 xr[4];
#pragma unroll
            for (int it = 0; it < 4; ++it) {
                int idx = it * 512 + tidx; int r = idx >> 5; int q = idx & 31;
                xr[it] = *(const float4*)(X + (size_t)r * 512 + ch * 128 + q * 4);
            }
            __syncthreads();            // prior chunk's A-reads done
#pragma unroll
            for (int it = 0; it < 4; ++it) {
                int idx = it * 512 + tidx; int r = idx >> 5; int k0 = (idx & 31) * 4;
                *(unsigned*)(smem + r * 128 + (k0 ^ ((r & 7) << 4))) =
                    f4_to_fp8x4(xr[it].x, xr[it].y, xr[it].z, xr[it].w);
            }
            __syncthreads();
            // compute: 2 kg (K=128) x 4 MFMA
#pragma unroll
            for (int kgl = 0; kgl < 2; ++kgl) {
                int kg = ch * 2 + kgl;
                int k0 = kgl * 64 + hi * 32;
                const unsigned char* r0 = smem + l31 * 128;
                const unsigned char* r1 = smem + (32 + l31) * 128;
                int8v a0 = mk8(*(const uint4*)(r0 + (k0 ^ swzx)),
                               *(const uint4*)(r0 + ((k0 + 16) ^ swzx)));
                int8v a1 = mk8(*(const uint4*)(r1 + (k0 ^ swzx)),
                               *(const uint4*)(r1 + ((k0 + 16) ^ swzx)));
                int8v w0 = mk8(wpA[(size_t)kg * 128], wpA[(size_t)kg * 128 + 1]);
                int8v w1 = mk8(wpB[(size_t)kg * 128], wpB[(size_t)kg * 128 + 1]);
                acc[0][0] = MFMASC(w0, a0, acc[0][0]);
                acc[0][1] = MFMASC(w0, a1, acc[0][1]);
                acc[1][0] = MFMASC(w1, a0, acc[1][0]);
                acc[1][1] = MFMASC(w1, a1, acc[1][1]);
            }
        }
        // epilogue -> h1 cols [p*512, p*512+512) (disjoint from X region)
#pragma unroll
        for (int c = 0; c < 2; ++c) {
            int mt = (p * 16 + wid * 2 + c) * 32;
#pragma unroll
            for (int rt = 0; rt < 2; ++rt) {
                int row = rt * 32 + l31;
#pragma unroll
                for (int q = 0; q < 4; ++q) {
                    int mg = mt + q * 8 + hi * 4;          // global h1 col, %4==0
                    float4 bb = *(const float4*)(biasp + mg);
                    float v0 = fmaxf(acc[c][rt][q * 4 + 0] + bb.x, 0.f);
                    float v1 = fmaxf(acc[c][rt][q * 4 + 1] + bb.y, 0.f);
                    float v2 = fmaxf(acc[c][rt][q * 4 + 2] + bb.z, 0.f);
                    float v3 = fmaxf(acc[c][rt][q * 4 + 3] + bb.w, 0.f);
                    *(unsigned*)(smem + 8192 + row * 1024 + (mg ^ swz)) =
                        f4_to_fp8x4(v0, v1, v2, v3);
                }
            }
        }
    }
    __syncthreads();

    // ======== L2: h2^T = W2^T(A) x h1(B), K=1024 (16 kg), CT=2, RT=2 ========
    {
        const uint4* wpA = pW2 + ((size_t)((wid * 2 + 0) * 16) * 64 + lane) * 2;
        const uint4* wpB = pW2 + ((size_t)((wid * 2 + 1) * 16) * 64 + lane) * 2;
        f32x16 acc[2][2];
#pragma unroll
        for (int c = 0; c < 2; ++c)
#pragma unroll
            for (int rt = 0; rt < 2; ++rt)
#pragma unroll
                for (int g = 0; g < 16; ++g) acc[c][rt][g] = 0.f;
#pragma unroll 1
        for (int kg = 0; kg < 16; ++kg) {
            int k0 = kg * 64 + hi * 32;
            const unsigned char* r0 = smem + 8192 + l31 * 1024;
            const unsigned char* r1 = smem + 8192 + (32 + l31) * 1024;
            int8v a0 = mk8(*(const uint4*)(r0 + (k0 ^ swz)),
                           *(const uint4*)(r0 + ((k0 + 16) ^ swz)));
            int8v a1 = mk8(*(const uint4*)(r1 + (k0 ^ swz)),
                           *(const uint4*)(r1 + ((k0 + 16) ^ swz)));
            int8v w0 = mk8(wpA[(size_t)kg * 128], wpA[(size_t)kg * 128 + 1]);
            int8v w1 = mk8(wpB[(size_t)kg * 128], wpB[(size_t)kg * 128 + 1]);
            acc[0][0] = MFMASC(w0, a0, acc[0][0]);
            acc[0][1] = MFMASC(w0, a1, acc[0][1]);
            acc[1][0] = MFMASC(w1, a0, acc[1][0]);
            acc[1][1] = MFMASC(w1, a1, acc[1][1]);
        }
        __syncthreads();   // ALL h1 reads done before h2 overwrites the region
        // epilogue -> h2 fp8 [64]x512B at [8192,40960)
#pragma unroll
        for (int c = 0; c < 2; ++c) {
            int mt = (wid * 2 + c) * 32;
#pragma unroll
            for (int rt = 0; rt < 2; ++rt) {
                int row = rt * 32 + l31;
#pragma unroll
                for (int q = 0; q < 4; ++q) {
                    int mg = mt + q * 8 + hi * 4;          // 0..511
                    float4 bb = *(const float4*)(biasp + 1024 + mg);
                    float v0 = fmaxf(acc[c][rt][q * 4 + 0] + bb.x, 0.f);
                    float v1 = fmaxf(acc[c][rt][q * 4 + 1] + bb.y, 0.f);
                    float v2 = fmaxf(acc[c][rt][q * 4 + 2] + bb.z, 0.f);
                    float v3 = fmaxf(acc[c][rt][q * 4 + 3] + bb.w, 0.f);
                    *(unsigned*)(smem + 8192 + row * 512 + (mg ^ swz)) =
                        f4_to_fp8x4(v0, v1, v2, v3);
                }
            }
        }
    }
    __syncthreads();

    // ======== L3: h3^T = W3^T(A) x h2(B), K=512 (8 kg), 8 waves CT=1, RT=2 ========
    {
        const uint4* wp = pW3 + ((size_t)(wid * 8) * 64 + lane) * 2;
        f32x16 acc3[2];
#pragma unroll
        for (int rt = 0; rt < 2; ++rt)
#pragma unroll
            for (int g = 0; g < 16; ++g) acc3[rt][g] = 0.f;
#pragma unroll 1
        for (int kg = 0; kg < 8; ++kg) {
            int k0 = kg * 64 + hi * 32;
            const unsigned char* r0 = smem + 8192 + l31 * 512;
            const unsigned char* r1 = smem + 8192 + (32 + l31) * 512;
            int8v a0 = mk8(*(const uint4*)(r0 + (k0 ^ swz)),
                           *(const uint4*)(r0 + ((k0 + 16) ^ swz)));
            int8v a1 = mk8(*(const uint4*)(r1 + (k0 ^ swz)),
                           *(const uint4*)(r1 + ((k0 + 16) ^ swz)));
            int8v w = mk8(wp[(size_t)kg * 128], wp[(size_t)kg * 128 + 1]);
            acc3[0] = MFMASC(w, a0, acc3[0]);
            acc3[1] = MFMASC(w, a1, acc3[1]);
        }
        // epilogue -> h3 bf16 [64]x512B at [40960,73728) (disjoint from h2 reads)
        int mt = wid * 32;
#pragma unroll
        for (int rt = 0; rt < 2; ++rt) {
            int row = rt * 32 + l31;
#pragma unroll
            for (int q = 0; q < 4; ++q) {
                int mg = mt + q * 8 + hi * 4;              // 0..255
                float4 bb = *(const float4*)(biasp + 1536 + mg);
                short4v s;
                s[0] = (short)f2bf(fmaxf(acc3[rt][q * 4 + 0] + bb.x, 0.f));
                s[1] = (short)f2bf(fmaxf(acc3[rt][q * 4 + 1] + bb.y, 0.f));
                s[2] = (short)f2bf(fmaxf(acc3[rt][q * 4 + 2] + bb.z, 0.f));
                s[3] = (short)f2bf(fmaxf(acc3[rt][q * 4 + 3] + bb.w, 0.f));
                *(short4v*)(smem + 40960 + row * 512 + ((mg * 2) ^ swz)) = s;
            }
        }
    }
    __syncthreads();

    // ======== L4 + loss: z = h3 . W4 + b4, 8 threads/row ========
    {
        int g  = tidx >> 3;      // row 0..63
        int t8 = tidx & 7;
        int gs = (g & 15) << 4;
        float sum = 0.f;
#pragma unroll
        for (int o = 0; o < 4; ++o) {
            int colb = t8 * 32 + o * 8;
            short4v v0 = *(const short4v*)(smem + 40960 + g * 512 + ((colb * 2) ^ gs));
            short4v v1 = *(const short4v*)(smem + 40960 + g * 512 + ((colb * 2 + 8) ^ gs));
#pragma unroll
            for (int j = 0; j < 4; ++j) {
                int c0 = colb + j, c1 = colb + 4 + j;
                if (c0 < 250) sum += bf2f((unsigned short)v0[j]) * W4[c0];
                if (c1 < 250) sum += bf2f((unsigned short)v1[j]) * W4[c1];
            }
        }
        sum += __shfl_down(sum, 4, 8);
        sum += __shfl_down(sum, 2, 8);
        sum += __shfl_down(sum, 1, 8);
        if (t8 == 0) {
            float z = sum + b4[0];
            bool fake = (grow0 < 65536);
            float spn = softplus(-z);
            red[g]      = fake ? spn : 0.f;               // loss_F part
            red[64 + g] = fake ? softplus(z) : spn;       // loss_D part
        }
    }
    __syncthreads();
    if (tidx == 0) {
        float pF = 0.f, pD = 0.f;
        for (int i = 0; i < 64; ++i) { pF += red[i]; pD += red[64 + i]; }
        partials[(size_t)blockIdx.x * 2]     = pF;
        partials[(size_t)blockIdx.x * 2 + 1] = pD;
    }
}

// ---------------- final reduction ----------------
__global__ void reduce_partials(const float* __restrict__ partials, int nblocks,
                                float* __restrict__ out) {
    __shared__ float sF[256], sD[256];
    float f = 0.f, d = 0.f;
    for (int i = threadIdx.x; i < nblocks; i += 256) {
        f += partials[2 * i];
        d += partials[2 * i + 1];
    }
    sF[threadIdx.x] = f; sD[threadIdx.x] = d;
    __syncthreads();
    for (int s = 128; s > 0; s >>= 1) {
        if (threadIdx.x < s) {
            sF[threadIdx.x] += sF[threadIdx.x + s];
            sD[threadIdx.x] += sD[threadIdx.x + s];
        }
        __syncthreads();
    }
    if (threadIdx.x == 0) { out[0] = sF[0]; out[1] = sD[0]; }
}

extern "C" void kernel_launch(void* const* d_in, const int* in_sizes, int n_in,
                              void* d_out, int out_size, void* d_ws, size_t ws_size,
                              hipStream_t stream) {
    const float* Xf = (const float*)d_in[0];   // repr_xy_hat [65536,512]
    const float* Xr = (const float*)d_in[1];   // repr_xy     [65536,512]
    const float* W1 = (const float*)d_in[2];   // [512,1000]
    const float* b1 = (const float*)d_in[3];
    const float* W2 = (const float*)d_in[4];   // [1000,500]
    const float* b2 = (const float*)d_in[5];
    const float* W3 = (const float*)d_in[6];   // [500,250]
    const float* b3 = (const float*)d_in[7];
    const float* W4 = (const float*)d_in[8];   // [250,1]
    const float* b4 = (const float*)d_in[9];

    // ws layout:
    // pW1: CT32 x KG8  x 64 x 32B = 512 KB   (32768 uint4)
    // pW2: CT16 x KG16 x 64 x 32B = 512 KB   (32768 uint4)
    // pW3: CT8  x KG8  x 64 x 32B = 128 KB   ( 8192 uint4)
    uint4* pW1 = (uint4*)d_ws;
    uint4* pW2 = pW1 + 32768;
    uint4* pW3 = pW2 + 32768;
    float* biasp = (float*)(pW3 + 8192);          // 1792 floats (pad to 2048)
    float* partials = biasp + 2048;               // 2048*2 floats

    pack_w_fp8g<<<(32 * 8 * 64) / 256, 256, 0, stream>>>(W1, pW1, 512, 1000, 8, 32);
    pack_w_fp8g<<<(16 * 16 * 64) / 256, 256, 0, stream>>>(W2, pW2, 1000, 500, 16, 16);
    pack_w_fp8g<<<(8 * 8 * 64) / 256, 256, 0, stream>>>(W3, pW3, 500, 250, 8, 8);
    pack_bias<<<7, 256, 0, stream>>>(b1, b2, b3, biasp);

    fused_mlp<<<2048, 512, 0, stream>>>(Xf, Xr, pW1, pW2, pW3,
                                        biasp, W4, b4, partials);

    reduce_partials<<<1, 256, 0, stream>>>(partials, 2048, (float*)d_out);
}